// Round 1
// baseline (3252.806 us; speedup 1.0000x reference)
//
#include <hip/hip_runtime.h>
#include <cmath>

#define BROWS 16384
#define CDIM  1024
#define NIT   16

typedef __attribute__((ext_vector_type(8))) short short8;
typedef __attribute__((ext_vector_type(4))) float floatx4;

__device__ __forceinline__ unsigned short f2bf(float f) {
  union { float f; unsigned u; } x; x.f = f;
  unsigned r = x.u + 0x7fffu + ((x.u >> 16) & 1u);  // RNE
  return (unsigned short)(r >> 16);
}
__device__ __forceinline__ float bf2f(unsigned short h) {
  union { float f; unsigned u; } x; x.u = ((unsigned)h) << 16;
  return x.f;
}

// ---- one-time prep: weights fp32 -> bf16, both [n][k] and transposed ----
__global__ void prep_weights(const float* __restrict__ W1, const float* __restrict__ W2,
                             const float* __restrict__ W3,
                             unsigned short* __restrict__ Wb, unsigned short* __restrict__ Wt) {
  int idx = blockIdx.x * 256 + threadIdx.x;   // 0 .. 3*2^20-1
  int m = idx >> 20;
  int r = (idx >> 10) & 1023;
  int c = idx & 1023;
  const float* W = (m == 0) ? W1 : ((m == 1) ? W2 : W3);
  unsigned short b = f2bf(W[r * CDIM + c]);
  Wb[idx] = b;                                // forward: B[n][k] = W[n][k]
  Wt[(m << 20) + c * CDIM + r] = b;           // backward: B[n][k] = W[k][n]
}

__global__ void conv_inputs(const float* __restrict__ y, const float* __restrict__ v,
                            unsigned short* __restrict__ ybf, unsigned short* __restrict__ wbf,
                            float* __restrict__ inner) {
  int i = blockIdx.x * 256 + threadIdx.x;     // exactly BROWS*CDIM threads
  ybf[i] = f2bf(y[i]);
  wbf[i] = f2bf(v[i]);
  if (i < NIT * BROWS) inner[i] = 0.f;
}

// ---- GEMM: C[m,n] = sum_k A[m,k]*B[n,k]; A: M x K bf16, B: N x K bf16 ----
// MODE 0: FWD   outB = bf16(elu(acc+bias)), outD = bf16(elu'(acc+bias))
// MODE 1: FWD3  outZ = acc + bias + yin   (fp32)
// MODE 2: BWD   outB = bf16(acc * Dm)
// MODE 3: BWD3  outB = bf16(acc); inner[row] += sum_n acc*vin
template <int MODE>
__global__ __launch_bounds__(256)
void gemm_k(const unsigned short* __restrict__ A,
            const unsigned short* __restrict__ Bm,
            const float* __restrict__ bias,
            const float* __restrict__ yin,
            const unsigned short* __restrict__ Dm,
            const float* __restrict__ vin,
            unsigned short* __restrict__ outB,
            unsigned short* __restrict__ outD,
            float* __restrict__ outZ,
            float* __restrict__ inner) {
  constexpr int K = CDIM, N = CDIM;
  __shared__ unsigned short At[128 * 32];
  __shared__ unsigned short Bt[128 * 32];
  const int t = threadIdx.x;
  const int m0 = blockIdx.y * 128;
  const int n0 = blockIdx.x * 128;
  const int wave = t >> 6, lane = t & 63;
  const int quad = lane >> 4, ln = lane & 15;
  const int wm = (wave >> 1) * 64, wn = (wave & 1) * 64;
  const int srow = t >> 2;          // 0..63
  const int koff = (t & 3) * 8;     // 0,8,16,24

  const unsigned short* gA0 = A + (size_t)(m0 + srow) * K + koff;
  const unsigned short* gA1 = gA0 + (size_t)64 * K;
  const unsigned short* gB0 = Bm + (size_t)(n0 + srow) * K + koff;
  const unsigned short* gB1 = gB0 + (size_t)64 * K;
  unsigned short* lA0 = &At[srow * 32 + koff];
  unsigned short* lA1 = lA0 + 64 * 32;
  unsigned short* lB0 = &Bt[srow * 32 + koff];
  unsigned short* lB1 = lB0 + 64 * 32;

  const unsigned short* rA = &At[(wm + ln) * 32 + quad * 8];
  const unsigned short* rB = &Bt[(wn + ln) * 32 + quad * 8];

  floatx4 acc[4][4];
#pragma unroll
  for (int i = 0; i < 4; i++)
#pragma unroll
    for (int j = 0; j < 4; j++) acc[i][j] = {0.f, 0.f, 0.f, 0.f};

  for (int k0 = 0; k0 < K; k0 += 32) {
    __builtin_amdgcn_global_load_lds((const __attribute__((address_space(1))) void*)(gA0 + k0),
                                     (__attribute__((address_space(3))) void*)lA0, 16, 0, 0);
    __builtin_amdgcn_global_load_lds((const __attribute__((address_space(1))) void*)(gA1 + k0),
                                     (__attribute__((address_space(3))) void*)lA1, 16, 0, 0);
    __builtin_amdgcn_global_load_lds((const __attribute__((address_space(1))) void*)(gB0 + k0),
                                     (__attribute__((address_space(3))) void*)lB0, 16, 0, 0);
    __builtin_amdgcn_global_load_lds((const __attribute__((address_space(1))) void*)(gB1 + k0),
                                     (__attribute__((address_space(3))) void*)lB1, 16, 0, 0);
    __syncthreads();
    short8 aF[4], bF[4];
#pragma unroll
    for (int mi = 0; mi < 4; mi++) aF[mi] = *(const short8*)(rA + mi * 512);
#pragma unroll
    for (int ni = 0; ni < 4; ni++) bF[ni] = *(const short8*)(rB + ni * 512);
#pragma unroll
    for (int mi = 0; mi < 4; mi++)
#pragma unroll
      for (int ni = 0; ni < 4; ni++)
        acc[mi][ni] = __builtin_amdgcn_mfma_f32_16x16x32_bf16(aF[mi], bF[ni], acc[mi][ni], 0, 0, 0);
    __syncthreads();
  }

  const int colBase = n0 + wn + ln;
  const int rowBase = m0 + wm + quad * 4;

  if (MODE == 0) {
#pragma unroll
    for (int ni = 0; ni < 4; ni++) {
      const int col = colBase + ni * 16;
      const float bv = bias[col];
#pragma unroll
      for (int mi = 0; mi < 4; mi++) {
        const int row = rowBase + mi * 16;
#pragma unroll
        for (int r = 0; r < 4; r++) {
          float p = acc[mi][ni][r] + bv;
          float e, dd;
          if (p > 0.f) { e = p; dd = 1.f; }
          else { e = expm1f(p); dd = e + 1.f; }
          size_t o = (size_t)(row + r) * N + col;
          outB[o] = f2bf(e);
          outD[o] = f2bf(dd);
        }
      }
    }
  } else if (MODE == 1) {
#pragma unroll
    for (int ni = 0; ni < 4; ni++) {
      const int col = colBase + ni * 16;
      const float bv = bias[col];
#pragma unroll
      for (int mi = 0; mi < 4; mi++) {
        const int row = rowBase + mi * 16;
#pragma unroll
        for (int r = 0; r < 4; r++) {
          size_t o = (size_t)(row + r) * N + col;
          outZ[o] = acc[mi][ni][r] + bv + yin[o];
        }
      }
    }
  } else if (MODE == 2) {
#pragma unroll
    for (int ni = 0; ni < 4; ni++) {
      const int col = colBase + ni * 16;
#pragma unroll
      for (int mi = 0; mi < 4; mi++) {
        const int row = rowBase + mi * 16;
#pragma unroll
        for (int r = 0; r < 4; r++) {
          size_t o = (size_t)(row + r) * N + col;
          outB[o] = f2bf(acc[mi][ni][r] * bf2f(Dm[o]));
        }
      }
    }
  } else {  // MODE 3
#pragma unroll
    for (int mi = 0; mi < 4; mi++) {
      const int row = rowBase + mi * 16;
      float rs[4] = {0.f, 0.f, 0.f, 0.f};
#pragma unroll
      for (int ni = 0; ni < 4; ni++) {
        const int col = colBase + ni * 16;
#pragma unroll
        for (int r = 0; r < 4; r++) {
          float val = acc[mi][ni][r];
          size_t o = (size_t)(row + r) * N + col;
          outB[o] = f2bf(val);
          rs[r] += val * vin[o];
        }
      }
#pragma unroll
      for (int r = 0; r < 4; r++) {
        float s = rs[r];
        s += __shfl_xor(s, 1);
        s += __shfl_xor(s, 2);
        s += __shfl_xor(s, 4);
        s += __shfl_xor(s, 8);
        if (ln == 0) atomicAdd(&inner[row + r], s);  // inner pre-offset per k
      }
    }
  }
}

__global__ void combine_ldj(const float* __restrict__ ldj_in, const float* __restrict__ inner,
                            float* __restrict__ out) {
  int b = blockIdx.x * 256 + threadIdx.x;
  if (b < BROWS) {
    float a = ldj_in[b];
#pragma unroll
    for (int k = 1; k <= NIT; k++) {
      float s = (k & 1) ? 1.f : -1.f;       // odd k: +, even k: -
      a += s * inner[(k - 1) * BROWS + b] / (float)k;
    }
    out[b] = a;
  }
}

extern "C" void kernel_launch(void* const* d_in, const int* in_sizes, int n_in,
                              void* d_out, int out_size, void* d_ws, size_t ws_size,
                              hipStream_t stream) {
  const float* y   = (const float*)d_in[0];
  const float* ldj = (const float*)d_in[1];
  const float* v   = (const float*)d_in[2];
  const float* W1  = (const float*)d_in[3];
  const float* b1  = (const float*)d_in[4];
  const float* W2  = (const float*)d_in[5];
  const float* b2  = (const float*)d_in[6];
  const float* W3  = (const float*)d_in[7];
  const float* b3  = (const float*)d_in[8];

  float* z_out   = (float*)d_out;                         // B*C fp32
  float* ldj_out = z_out + (size_t)BROWS * CDIM;          // B fp32

  const size_t MC = (size_t)BROWS * CDIM;                 // 16M elems
  const size_t WW = (size_t)3 * CDIM * CDIM;              // 3M elems
  unsigned short* Wb    = (unsigned short*)d_ws;          // 6 MB
  unsigned short* Wt    = Wb + WW;                        // 6 MB
  float*          inner = (float*)(Wt + WW);              // 1 MB
  unsigned short* ybf   = (unsigned short*)(inner + NIT * BROWS);
  unsigned short* ua    = ybf + MC;                       // 32 MB each
  unsigned short* ub    = ua + MC;
  unsigned short* wv    = ub + MC;
  unsigned short* d1    = wv + MC;
  unsigned short* d2    = d1 + MC;

  prep_weights<<<(3 * CDIM * CDIM) / 256, 256, 0, stream>>>(W1, W2, W3, Wb, Wt);
  conv_inputs<<<(BROWS * CDIM) / 256, 256, 0, stream>>>(y, v, ybf, wv, inner);

  dim3 grid(CDIM / 128, BROWS / 128);  // (8, 128)

  // forward: h1=elu(y@W1^T+b1), h2=elu(h1@W2^T+b2), z=y+h2@W3^T+b3
  gemm_k<0><<<grid, 256, 0, stream>>>(ybf, Wb,                 b1, nullptr, nullptr, nullptr, ua, d1, nullptr, nullptr);
  gemm_k<0><<<grid, 256, 0, stream>>>(ua,  Wb + (1 << 20),     b2, nullptr, nullptr, nullptr, ub, d2, nullptr, nullptr);
  gemm_k<1><<<grid, 256, 0, stream>>>(ub,  Wb + (2 << 20),     b3, y,       nullptr, nullptr, nullptr, nullptr, z_out, nullptr);

  // power series: w <- ((w@W3)*d2 @ W2)*d1 @ W1 ; inner_k = <w, v>
  for (int k = 1; k <= NIT; k++) {
    gemm_k<2><<<grid, 256, 0, stream>>>(wv, Wt + (2 << 20), nullptr, nullptr, d2, nullptr, ua, nullptr, nullptr, nullptr);
    gemm_k<2><<<grid, 256, 0, stream>>>(ua, Wt + (1 << 20), nullptr, nullptr, d1, nullptr, ub, nullptr, nullptr, nullptr);
    gemm_k<3><<<grid, 256, 0, stream>>>(ub, Wt,             nullptr, nullptr, nullptr, v, wv, nullptr, nullptr, inner + (size_t)(k - 1) * BROWS);
  }

  combine_ldj<<<(BROWS + 255) / 256, 256, 0, stream>>>(ldj, inner, ldj_out);
}

// Round 2
// 2998.922 us; speedup vs baseline: 1.0847x; 1.0847x over previous
//
#include <hip/hip_runtime.h>
#include <cmath>

#define BROWS 16384
#define CDIM  1024
#define NIT   16

typedef __attribute__((ext_vector_type(8))) short short8;
typedef __attribute__((ext_vector_type(4))) short short4v;
typedef __attribute__((ext_vector_type(4))) float floatx4;

__device__ __forceinline__ unsigned short f2bf(float f) {
  union { float f; unsigned u; } x; x.f = f;
  unsigned r = x.u + 0x7fffu + ((x.u >> 16) & 1u);  // RNE
  return (unsigned short)(r >> 16);
}
__device__ __forceinline__ float bf2f(unsigned short h) {
  union { float f; unsigned u; } x; x.u = ((unsigned)h) << 16;
  return x.f;
}

// ---- one-time prep: weights fp32 -> bf16, both [n][k] and transposed ----
__global__ void prep_weights(const float* __restrict__ W1, const float* __restrict__ W2,
                             const float* __restrict__ W3,
                             unsigned short* __restrict__ Wb, unsigned short* __restrict__ Wt) {
  int idx = blockIdx.x * 256 + threadIdx.x;   // 0 .. 3*2^20-1
  int m = idx >> 20;
  int r = (idx >> 10) & 1023;
  int c = idx & 1023;
  const float* W = (m == 0) ? W1 : ((m == 1) ? W2 : W3);
  unsigned short b = f2bf(W[r * CDIM + c]);
  Wb[idx] = b;                                // forward: B[n][k] = W[n][k]
  Wt[(m << 20) + c * CDIM + r] = b;           // backward: B[n][k] = W[k][n]
}

__global__ void conv_inputs(const float* __restrict__ y, const float* __restrict__ v,
                            unsigned short* __restrict__ ybf, unsigned short* __restrict__ wbf,
                            float* __restrict__ inner) {
  int i = (blockIdx.x * 256 + threadIdx.x) * 4;   // vectorized x4
  floatx4 yv = *(const floatx4*)(y + i);
  floatx4 vv = *(const floatx4*)(v + i);
  short4v a, b;
#pragma unroll
  for (int r = 0; r < 4; r++) { a[r] = (short)f2bf(yv[r]); b[r] = (short)f2bf(vv[r]); }
  *(short4v*)(ybf + i) = a;
  *(short4v*)(wbf + i) = b;
  if (i < NIT * BROWS) *(floatx4*)(inner + i) = floatx4{0.f, 0.f, 0.f, 0.f};
}

// ---- GEMM: C[m,n] = sum_k A[m,k]*B[n,k]; A: M x K bf16, B: N x K bf16 ----
// MODE 0: FWD   outB = bf16(elu(acc+bias)), outD = bf16(elu'(acc+bias))
// MODE 1: FWD3  outZ = acc + bias + yin   (fp32)
// MODE 2: BWD   outB = bf16(acc * Dm)
// MODE 3: BWD3  outB = bf16(acc); inner[row] += sum_n acc*vin
template <int MODE>
__global__ __launch_bounds__(256)
void gemm_k(const unsigned short* __restrict__ A,
            const unsigned short* __restrict__ Bm,
            const float* __restrict__ bias,
            const float* __restrict__ yin,
            const unsigned short* __restrict__ Dm,
            const float* __restrict__ vin,
            unsigned short* __restrict__ outB,
            unsigned short* __restrict__ outD,
            float* __restrict__ outZ,
            float* __restrict__ inner) {
  constexpr int K = CDIM, N = CDIM;
  // K-loop staging (16 KB) and epilogue transpose tile (34 KB) share one buffer.
  __shared__ unsigned short smem[128 * 136];
  unsigned short* At = smem;              // 128x32
  unsigned short* Bt = smem + 128 * 32;   // 128x32
  unsigned short* Ct = smem;              // 128 x 136 (pad 8) epilogue tile

  const int t = threadIdx.x;
  // XCD swizzle: assume dispatch round-robins XCDs by linear block id.
  // XCD x owns m-tiles [x*16, x*16+16); within an XCD, n-tile cycles fastest
  // so the 2 MB weight + one 256 KB A-tile live in the 4 MB per-XCD L2.
  const int lb = blockIdx.x;              // 0..1023
  const int s = lb >> 3;
  const int m0 = ((lb & 7) * 16 + (s >> 3)) * 128;
  const int n0 = (s & 7) * 128;

  const int wave = t >> 6, lane = t & 63;
  const int quad = lane >> 4, ln = lane & 15;
  const int wm = (wave >> 1) * 64, wn = (wave & 1) * 64;
  const int srow = t >> 2;          // 0..63
  const int koff = (t & 3) * 8;     // 0,8,16,24

  const unsigned short* gA0 = A + (size_t)(m0 + srow) * K + koff;
  const unsigned short* gA1 = gA0 + (size_t)64 * K;
  const unsigned short* gB0 = Bm + (size_t)(n0 + srow) * K + koff;
  const unsigned short* gB1 = gB0 + (size_t)64 * K;
  unsigned short* lA0 = &At[srow * 32 + koff];
  unsigned short* lA1 = lA0 + 64 * 32;
  unsigned short* lB0 = &Bt[srow * 32 + koff];
  unsigned short* lB1 = lB0 + 64 * 32;

  const unsigned short* rA = &At[(wm + ln) * 32 + quad * 8];
  const unsigned short* rB = &Bt[(wn + ln) * 32 + quad * 8];

  floatx4 acc[4][4];
#pragma unroll
  for (int i = 0; i < 4; i++)
#pragma unroll
    for (int j = 0; j < 4; j++) acc[i][j] = {0.f, 0.f, 0.f, 0.f};

  for (int k0 = 0; k0 < K; k0 += 32) {
    __builtin_amdgcn_global_load_lds((const __attribute__((address_space(1))) void*)(gA0 + k0),
                                     (__attribute__((address_space(3))) void*)lA0, 16, 0, 0);
    __builtin_amdgcn_global_load_lds((const __attribute__((address_space(1))) void*)(gA1 + k0),
                                     (__attribute__((address_space(3))) void*)lA1, 16, 0, 0);
    __builtin_amdgcn_global_load_lds((const __attribute__((address_space(1))) void*)(gB0 + k0),
                                     (__attribute__((address_space(3))) void*)lB0, 16, 0, 0);
    __builtin_amdgcn_global_load_lds((const __attribute__((address_space(1))) void*)(gB1 + k0),
                                     (__attribute__((address_space(3))) void*)lB1, 16, 0, 0);
    __syncthreads();
    short8 aF[4], bF[4];
#pragma unroll
    for (int mi = 0; mi < 4; mi++) aF[mi] = *(const short8*)(rA + mi * 512);
#pragma unroll
    for (int ni = 0; ni < 4; ni++) bF[ni] = *(const short8*)(rB + ni * 512);
#pragma unroll
    for (int mi = 0; mi < 4; mi++)
#pragma unroll
      for (int ni = 0; ni < 4; ni++)
        acc[mi][ni] = __builtin_amdgcn_mfma_f32_16x16x32_bf16(aF[mi], bF[ni], acc[mi][ni], 0, 0, 0);
    __syncthreads();
  }

  // ---- epilogue: stage C-layout accumulator into LDS (bf16), then do all
  // global I/O row-major coalesced (16 B / lane) ----
  const int lrow = wm + quad * 4;
  const int lcol = wn + ln;

  if (MODE == 0) {
    float bv[4];
#pragma unroll
    for (int ni = 0; ni < 4; ni++) bv[ni] = bias[n0 + lcol + ni * 16];
#pragma unroll
    for (int mi = 0; mi < 4; mi++)
#pragma unroll
      for (int ni = 0; ni < 4; ni++)
#pragma unroll
        for (int r = 0; r < 4; r++) {
          float p = acc[mi][ni][r] + bv[ni];
          float e = (p > 0.f) ? p : expm1f(p);
          Ct[(lrow + mi * 16 + r) * 136 + lcol + ni * 16] = f2bf(e);
        }
  } else {
#pragma unroll
    for (int mi = 0; mi < 4; mi++)
#pragma unroll
      for (int ni = 0; ni < 4; ni++)
#pragma unroll
        for (int r = 0; r < 4; r++)
          Ct[(lrow + mi * 16 + r) * 136 + lcol + ni * 16] = f2bf(acc[mi][ni][r]);
  }
  __syncthreads();

  const int rrow = t >> 4;          // 0..15
  const int rcol = (t & 15) * 8;    // 0..120
#pragma unroll
  for (int it = 0; it < 8; it++) {
    const int lr = it * 16 + rrow;
    short8 val = *(const short8*)&Ct[lr * 136 + rcol];
    const size_t o = (size_t)(m0 + lr) * N + (n0 + rcol);
    if (MODE == 0) {
      *(short8*)&outB[o] = val;
      short8 dd;
#pragma unroll
      for (int i = 0; i < 8; i++) {
        float e = bf2f((unsigned short)val[i]);
        dd[i] = (short)f2bf(e > 0.f ? 1.f : e + 1.f);   // elu' from staged elu
      }
      *(short8*)&outD[o] = dd;
    } else if (MODE == 1) {
      const floatx4 y0 = *(const floatx4*)&yin[o];
      const floatx4 y1 = *(const floatx4*)&yin[o + 4];
      const floatx4 b0 = *(const floatx4*)&bias[n0 + rcol];
      const floatx4 b1 = *(const floatx4*)&bias[n0 + rcol + 4];
      floatx4 z0, z1;
#pragma unroll
      for (int i = 0; i < 4; i++) {
        z0[i] = bf2f((unsigned short)val[i]) + b0[i] + y0[i];
        z1[i] = bf2f((unsigned short)val[i + 4]) + b1[i] + y1[i];
      }
      *(floatx4*)&outZ[o] = z0;
      *(floatx4*)&outZ[o + 4] = z1;
    } else if (MODE == 2) {
      short8 d = *(const short8*)&Dm[o];
      short8 ov;
#pragma unroll
      for (int i = 0; i < 8; i++)
        ov[i] = (short)f2bf(bf2f((unsigned short)val[i]) * bf2f((unsigned short)d[i]));
      *(short8*)&outB[o] = ov;
    } else {  // MODE 3
      *(short8*)&outB[o] = val;
      const floatx4 v0 = *(const floatx4*)&vin[o];
      const floatx4 v1 = *(const floatx4*)&vin[o + 4];
      float ps = 0.f;
#pragma unroll
      for (int i = 0; i < 4; i++) {
        ps += bf2f((unsigned short)val[i]) * v0[i];
        ps += bf2f((unsigned short)val[i + 4]) * v1[i];
      }
      ps += __shfl_xor(ps, 1);
      ps += __shfl_xor(ps, 2);
      ps += __shfl_xor(ps, 4);
      ps += __shfl_xor(ps, 8);
      if ((t & 15) == 0) atomicAdd(&inner[m0 + lr], ps);
    }
  }
}

__global__ void combine_ldj(const float* __restrict__ ldj_in, const float* __restrict__ inner,
                            float* __restrict__ out) {
  int b = blockIdx.x * 256 + threadIdx.x;
  if (b < BROWS) {
    float a = ldj_in[b];
#pragma unroll
    for (int k = 1; k <= NIT; k++) {
      float s = (k & 1) ? 1.f : -1.f;       // odd k: +, even k: -
      a += s * inner[(k - 1) * BROWS + b] / (float)k;
    }
    out[b] = a;
  }
}

extern "C" void kernel_launch(void* const* d_in, const int* in_sizes, int n_in,
                              void* d_out, int out_size, void* d_ws, size_t ws_size,
                              hipStream_t stream) {
  const float* y   = (const float*)d_in[0];
  const float* ldj = (const float*)d_in[1];
  const float* v   = (const float*)d_in[2];
  const float* W1  = (const float*)d_in[3];
  const float* b1  = (const float*)d_in[4];
  const float* W2  = (const float*)d_in[5];
  const float* b2  = (const float*)d_in[6];
  const float* W3  = (const float*)d_in[7];
  const float* b3  = (const float*)d_in[8];

  float* z_out   = (float*)d_out;                         // B*C fp32
  float* ldj_out = z_out + (size_t)BROWS * CDIM;          // B fp32

  const size_t MC = (size_t)BROWS * CDIM;                 // 16M elems
  const size_t WW = (size_t)3 * CDIM * CDIM;              // 3M elems
  unsigned short* Wb    = (unsigned short*)d_ws;          // 6 MB
  unsigned short* Wt    = Wb + WW;                        // 6 MB
  float*          inner = (float*)(Wt + WW);              // 1 MB
  unsigned short* ybf   = (unsigned short*)(inner + NIT * BROWS);
  unsigned short* ua    = ybf + MC;                       // 32 MB each
  unsigned short* ub    = ua + MC;
  unsigned short* wv    = ub + MC;
  unsigned short* d1    = wv + MC;
  unsigned short* d2    = d1 + MC;

  prep_weights<<<(3 * CDIM * CDIM) / 256, 256, 0, stream>>>(W1, W2, W3, Wb, Wt);
  conv_inputs<<<(BROWS * CDIM) / (256 * 4), 256, 0, stream>>>(y, v, ybf, wv, inner);

  dim3 grid(1024);  // 1D, XCD-swizzled inside the kernel

  // forward: h1=elu(y@W1^T+b1), h2=elu(h1@W2^T+b2), z=y+h2@W3^T+b3
  gemm_k<0><<<grid, 256, 0, stream>>>(ybf, Wb,             b1, nullptr, nullptr, nullptr, ua, d1, nullptr, nullptr);
  gemm_k<0><<<grid, 256, 0, stream>>>(ua,  Wb + (1 << 20), b2, nullptr, nullptr, nullptr, ub, d2, nullptr, nullptr);
  gemm_k<1><<<grid, 256, 0, stream>>>(ub,  Wb + (2 << 20), b3, y,       nullptr, nullptr, nullptr, nullptr, z_out, nullptr);

  // power series: w <- ((w@W3)*d2 @ W2)*d1 @ W1 ; inner_k = <w, v>
  for (int k = 1; k <= NIT; k++) {
    gemm_k<2><<<grid, 256, 0, stream>>>(wv, Wt + (2 << 20), nullptr, nullptr, d2, nullptr, ua, nullptr, nullptr, nullptr);
    gemm_k<2><<<grid, 256, 0, stream>>>(ua, Wt + (1 << 20), nullptr, nullptr, d1, nullptr, ub, nullptr, nullptr, nullptr);
    gemm_k<3><<<grid, 256, 0, stream>>>(ub, Wt,             nullptr, nullptr, nullptr, v, wv, nullptr, nullptr, inner + (size_t)(k - 1) * BROWS);
  }

  combine_ldj<<<(BROWS + 255) / 256, 256, 0, stream>>>(ldj, inner, ldj_out);
}

// Round 3
// 2798.869 us; speedup vs baseline: 1.1622x; 1.0715x over previous
//
#include <hip/hip_runtime.h>
#include <cmath>

#define BROWS 16384
#define CDIM  1024
#define NIT   16

typedef __attribute__((ext_vector_type(8))) short short8;
typedef __attribute__((ext_vector_type(4))) short short4v;
typedef __attribute__((ext_vector_type(4))) float floatx4;

__device__ __forceinline__ unsigned short f2bf(float f) {
  union { float f; unsigned u; } x; x.f = f;
  unsigned r = x.u + 0x7fffu + ((x.u >> 16) & 1u);  // RNE
  return (unsigned short)(r >> 16);
}
__device__ __forceinline__ float bf2f(unsigned short h) {
  union { float f; unsigned u; } x; x.u = ((unsigned)h) << 16;
  return x.f;
}

// ---- one-time prep: weights fp32 -> bf16, both [n][k] and transposed ----
__global__ void prep_weights(const float* __restrict__ W1, const float* __restrict__ W2,
                             const float* __restrict__ W3,
                             unsigned short* __restrict__ Wb, unsigned short* __restrict__ Wt) {
  int idx = blockIdx.x * 256 + threadIdx.x;   // 0 .. 3*2^20-1
  int m = idx >> 20;
  int r = (idx >> 10) & 1023;
  int c = idx & 1023;
  const float* W = (m == 0) ? W1 : ((m == 1) ? W2 : W3);
  unsigned short b = f2bf(W[r * CDIM + c]);
  Wb[idx] = b;                                // forward: B[n][k] = W[n][k]
  Wt[(m << 20) + c * CDIM + r] = b;           // backward: B[n][k] = W[k][n]
}

__global__ void conv_inputs(const float* __restrict__ y, const float* __restrict__ v,
                            unsigned short* __restrict__ ybf, unsigned short* __restrict__ wbf,
                            float* __restrict__ inner) {
  int i = (blockIdx.x * 256 + threadIdx.x) * 4;   // vectorized x4
  floatx4 yv = *(const floatx4*)(y + i);
  floatx4 vv = *(const floatx4*)(v + i);
  short4v a, b;
#pragma unroll
  for (int r = 0; r < 4; r++) { a[r] = (short)f2bf(yv[r]); b[r] = (short)f2bf(vv[r]); }
  *(short4v*)(ybf + i) = a;
  *(short4v*)(wbf + i) = b;
  if (i < NIT * BROWS) *(floatx4*)(inner + i) = floatx4{0.f, 0.f, 0.f, 0.f};
}

// v fp32 -> bf16, into the (now free) ybf buffer; runs after GEMM1 on stream
__global__ void conv_v(const float* __restrict__ v, unsigned short* __restrict__ vb) {
  int i = (blockIdx.x * 256 + threadIdx.x) * 8;
  floatx4 a = *(const floatx4*)(v + i);
  floatx4 b = *(const floatx4*)(v + i + 4);
  short8 o;
#pragma unroll
  for (int r = 0; r < 4; r++) { o[r] = (short)f2bf(a[r]); o[r + 4] = (short)f2bf(b[r]); }
  *(short8*)(vb + i) = o;
}

// ---- GEMM: C[m,n] = sum_k A[m,k]*B[n,k]; A: M x K bf16, B: N x K bf16 ----
// MODE 0: FWD   outB = bf16(elu(acc+bias)), outD = bf16(elu'(acc+bias))
// MODE 1: FWD3  outZ = acc + bias + yin   (fp32)
// MODE 2: BWD   outB = bf16(acc * Dm)
// MODE 3: BWD3  outB = bf16(acc); inner[row] += sum_n acc*vin
template <int MODE>
__global__ __launch_bounds__(256)
void gemm_k(const unsigned short* __restrict__ A,
            const unsigned short* __restrict__ Bm,
            const float* __restrict__ bias,
            const float* __restrict__ yin,
            const unsigned short* __restrict__ Dm,
            const unsigned short* __restrict__ vin,
            unsigned short* __restrict__ outB,
            unsigned short* __restrict__ outD,
            float* __restrict__ outZ,
            float* __restrict__ inner) {
  constexpr int K = CDIM, N = CDIM;
  // 33792 B: double-buffered staging (2 x 8192 elems) overlapped with the
  // 128x132 bf16 epilogue transpose tile.
  __shared__ unsigned short smem[128 * 132];

  const int t = threadIdx.x;
  // XCD swizzle: linear block id round-robins XCDs; XCD x owns m-slab x.
  const int lb = blockIdx.x;              // 0..1023
  const int s = lb >> 3;
  const int m0 = ((lb & 7) * 16 + (s >> 3)) * 128;
  const int n0 = (s & 7) * 128;

  const int wave = t >> 6, lane = t & 63;
  const int quad = lane >> 4, ln = lane & 15;
  const int wm = (wave >> 1) * 64, wn = (wave & 1) * 64;
  const int srow = t >> 2;                      // 0..63
  const int kx = ((srow >> 1) & 3) * 8;         // XOR swizzle (per pair of rows)
  const int koff = ((t & 3) * 8) ^ kx;          // swizzled k-offset in GLOBAL addr

  const unsigned short* gA = A + (size_t)(m0 + srow) * K + koff;
  const unsigned short* gB = Bm + (size_t)(n0 + srow) * K + koff;
  // LDS dest is lane-linear (byte 16*t within each 64x32 half) as required by
  // global_load_lds; the swizzle lives in the global column instead.
  const int ld = t * 8;                         // elems

  // compute-phase read offsets (swizzle folded in; invariant across mi/ni)
  const int xorA = (((wm + ln) >> 1) & 3) * 8;
  const int xorB = (((wn + ln) >> 1) & 3) * 8;
  const int rAoff = (wm + ln) * 32 + ((quad * 8) ^ xorA);
  const int rBoff = 4096 + (wn + ln) * 32 + ((quad * 8) ^ xorB);

  floatx4 acc[4][4];
#pragma unroll
  for (int i = 0; i < 4; i++)
#pragma unroll
    for (int j = 0; j < 4; j++) acc[i][j] = {0.f, 0.f, 0.f, 0.f};

#define STAGE(k0, bufb)                                                                        \
  do {                                                                                         \
    __builtin_amdgcn_global_load_lds((const __attribute__((address_space(1))) void*)(gA + (k0)), \
        (__attribute__((address_space(3))) void*)&smem[(bufb) + ld], 16, 0, 0);                \
    __builtin_amdgcn_global_load_lds((const __attribute__((address_space(1))) void*)(gA + (size_t)64 * K + (k0)), \
        (__attribute__((address_space(3))) void*)&smem[(bufb) + 2048 + ld], 16, 0, 0);         \
    __builtin_amdgcn_global_load_lds((const __attribute__((address_space(1))) void*)(gB + (k0)), \
        (__attribute__((address_space(3))) void*)&smem[(bufb) + 4096 + ld], 16, 0, 0);         \
    __builtin_amdgcn_global_load_lds((const __attribute__((address_space(1))) void*)(gB + (size_t)64 * K + (k0)), \
        (__attribute__((address_space(3))) void*)&smem[(bufb) + 6144 + ld], 16, 0, 0);         \
  } while (0)

  STAGE(0, 0);
  for (int k0 = 0; k0 < K; k0 += 32) {
    const int cb = ((k0 >> 5) & 1) * 8192;
    __syncthreads();                    // waits tile-k loads; tile-(k+1) loads below overlap compute
    if (k0 + 32 < K) STAGE(k0 + 32, 8192 - cb);
    short8 aF[4], bF[4];
#pragma unroll
    for (int mi = 0; mi < 4; mi++) aF[mi] = *(const short8*)&smem[cb + rAoff + mi * 512];
#pragma unroll
    for (int ni = 0; ni < 4; ni++) bF[ni] = *(const short8*)&smem[cb + rBoff + ni * 512];
#pragma unroll
    for (int mi = 0; mi < 4; mi++)
#pragma unroll
      for (int ni = 0; ni < 4; ni++)
        acc[mi][ni] = __builtin_amdgcn_mfma_f32_16x16x32_bf16(aF[mi], bF[ni], acc[mi][ni], 0, 0, 0);
  }
  __syncthreads();                      // staging done; smem becomes Ct
#undef STAGE

  // ---- epilogue: C-layout -> LDS (stride 132: conflict-free scalar writes,
  // 8B-aligned b64 reads), then coalesced global I/O ----
  unsigned short* Ct = smem;
  const int lrow = wm + quad * 4;
  const int lcol = wn + ln;

  if (MODE == 0) {
    float bv[4];
#pragma unroll
    for (int ni = 0; ni < 4; ni++) bv[ni] = bias[n0 + lcol + ni * 16];
#pragma unroll
    for (int mi = 0; mi < 4; mi++)
#pragma unroll
      for (int ni = 0; ni < 4; ni++)
#pragma unroll
        for (int r = 0; r < 4; r++) {
          float p = acc[mi][ni][r] + bv[ni];
          float e = (p > 0.f) ? p : expm1f(p);
          Ct[(lrow + mi * 16 + r) * 132 + lcol + ni * 16] = f2bf(e);
        }
  } else {
#pragma unroll
    for (int mi = 0; mi < 4; mi++)
#pragma unroll
      for (int ni = 0; ni < 4; ni++)
#pragma unroll
        for (int r = 0; r < 4; r++)
          Ct[(lrow + mi * 16 + r) * 132 + lcol + ni * 16] = f2bf(acc[mi][ni][r]);
  }
  __syncthreads();

  const int rrow = t >> 4;          // 0..15
  const int rcol = (t & 15) * 8;    // 0..120
#pragma unroll
  for (int it = 0; it < 8; it++) {
    const int lr = it * 16 + rrow;
    short4v v0 = *(const short4v*)&Ct[lr * 132 + rcol];
    short4v v1 = *(const short4v*)&Ct[lr * 132 + rcol + 4];
    short8 val;
#pragma unroll
    for (int i = 0; i < 4; i++) { val[i] = v0[i]; val[i + 4] = v1[i]; }
    const size_t o = (size_t)(m0 + lr) * N + (n0 + rcol);
    if (MODE == 0) {
      *(short8*)&outB[o] = val;
      short8 dd;
#pragma unroll
      for (int i = 0; i < 8; i++) {
        float e = bf2f((unsigned short)val[i]);
        dd[i] = (short)f2bf(e > 0.f ? 1.f : e + 1.f);   // elu' from staged elu
      }
      *(short8*)&outD[o] = dd;
    } else if (MODE == 1) {
      const floatx4 y0 = *(const floatx4*)&yin[o];
      const floatx4 y1 = *(const floatx4*)&yin[o + 4];
      const floatx4 b0 = *(const floatx4*)&bias[n0 + rcol];
      const floatx4 b1 = *(const floatx4*)&bias[n0 + rcol + 4];
      floatx4 z0, z1;
#pragma unroll
      for (int i = 0; i < 4; i++) {
        z0[i] = bf2f((unsigned short)val[i]) + b0[i] + y0[i];
        z1[i] = bf2f((unsigned short)val[i + 4]) + b1[i] + y1[i];
      }
      *(floatx4*)&outZ[o] = z0;
      *(floatx4*)&outZ[o + 4] = z1;
    } else if (MODE == 2) {
      short8 d = *(const short8*)&Dm[o];
      short8 ov;
#pragma unroll
      for (int i = 0; i < 8; i++)
        ov[i] = (short)f2bf(bf2f((unsigned short)val[i]) * bf2f((unsigned short)d[i]));
      *(short8*)&outB[o] = ov;
    } else {  // MODE 3
      *(short8*)&outB[o] = val;
      short8 vv = *(const short8*)&vin[o];
      float ps = 0.f;
#pragma unroll
      for (int i = 0; i < 8; i++)
        ps += bf2f((unsigned short)val[i]) * bf2f((unsigned short)vv[i]);
      ps += __shfl_xor(ps, 1);
      ps += __shfl_xor(ps, 2);
      ps += __shfl_xor(ps, 4);
      ps += __shfl_xor(ps, 8);
      if ((t & 15) == 0) atomicAdd(&inner[m0 + lr], ps);
    }
  }
}

__global__ void combine_ldj(const float* __restrict__ ldj_in, const float* __restrict__ inner,
                            float* __restrict__ out) {
  int b = blockIdx.x * 256 + threadIdx.x;
  if (b < BROWS) {
    float a = ldj_in[b];
#pragma unroll
    for (int k = 1; k <= NIT; k++) {
      float s = (k & 1) ? 1.f : -1.f;       // odd k: +, even k: -
      a += s * inner[(k - 1) * BROWS + b] / (float)k;
    }
    out[b] = a;
  }
}

extern "C" void kernel_launch(void* const* d_in, const int* in_sizes, int n_in,
                              void* d_out, int out_size, void* d_ws, size_t ws_size,
                              hipStream_t stream) {
  const float* y   = (const float*)d_in[0];
  const float* ldj = (const float*)d_in[1];
  const float* v   = (const float*)d_in[2];
  const float* W1  = (const float*)d_in[3];
  const float* b1  = (const float*)d_in[4];
  const float* W2  = (const float*)d_in[5];
  const float* b2  = (const float*)d_in[6];
  const float* W3  = (const float*)d_in[7];
  const float* b3  = (const float*)d_in[8];

  float* z_out   = (float*)d_out;                         // B*C fp32
  float* ldj_out = z_out + (size_t)BROWS * CDIM;          // B fp32

  const size_t MC = (size_t)BROWS * CDIM;                 // 16M elems
  const size_t WW = (size_t)3 * CDIM * CDIM;              // 3M elems
  unsigned short* Wb    = (unsigned short*)d_ws;          // 6 MB
  unsigned short* Wt    = Wb + WW;                        // 6 MB
  float*          inner = (float*)(Wt + WW);              // 1 MB
  unsigned short* ybf   = (unsigned short*)(inner + NIT * BROWS);
  unsigned short* ua    = ybf + MC;                       // 32 MB each
  unsigned short* ub    = ua + MC;
  unsigned short* wv    = ub + MC;
  unsigned short* d1    = wv + MC;
  unsigned short* d2    = d1 + MC;

  prep_weights<<<(3 * CDIM * CDIM) / 256, 256, 0, stream>>>(W1, W2, W3, Wb, Wt);
  conv_inputs<<<(BROWS * CDIM) / (256 * 4), 256, 0, stream>>>(y, v, ybf, wv, inner);

  dim3 grid(1024);  // 1D, XCD-swizzled inside the kernel

  // forward: h1=elu(y@W1^T+b1), h2=elu(h1@W2^T+b2), z=y+h2@W3^T+b3
  gemm_k<0><<<grid, 256, 0, stream>>>(ybf, Wb,             b1, nullptr, nullptr, nullptr, ua, d1, nullptr, nullptr);
  // ybf is free after GEMM1 -> reuse it for bf16(v)
  conv_v<<<(BROWS * CDIM) / (256 * 8), 256, 0, stream>>>(v, ybf);
  gemm_k<0><<<grid, 256, 0, stream>>>(ua,  Wb + (1 << 20), b2, nullptr, nullptr, nullptr, ub, d2, nullptr, nullptr);
  gemm_k<1><<<grid, 256, 0, stream>>>(ub,  Wb + (2 << 20), b3, y,       nullptr, nullptr, nullptr, nullptr, z_out, nullptr);

  // power series: w <- ((w@W3)*d2 @ W2)*d1 @ W1 ; inner_k = <w, v>
  for (int k = 1; k <= NIT; k++) {
    gemm_k<2><<<grid, 256, 0, stream>>>(wv, Wt + (2 << 20), nullptr, nullptr, d2, nullptr, ua, nullptr, nullptr, nullptr);
    gemm_k<2><<<grid, 256, 0, stream>>>(ua, Wt + (1 << 20), nullptr, nullptr, d1, nullptr, ub, nullptr, nullptr, nullptr);
    gemm_k<3><<<grid, 256, 0, stream>>>(ub, Wt,             nullptr, nullptr, nullptr, ybf, wv, nullptr, nullptr, inner + (size_t)(k - 1) * BROWS);
  }

  combine_ldj<<<(BROWS + 255) / 256, 256, 0, stream>>>(ldj, inner, ldj_out);
}